// Round 14
// baseline (707.183 us; speedup 1.0000x reference)
//
#include <hip/hip_runtime.h>
#include <cstddef>
#include <cstdint>

typedef unsigned short ushort_t;
typedef unsigned char  u8_t;
typedef __attribute__((ext_vector_type(4))) float f32x4;
typedef __attribute__((ext_vector_type(8))) short bf16x8;
typedef __attribute__((ext_vector_type(2))) unsigned long long u64x2;

#define BB   8192
#define AA   16
#define BA   131072

// ---------------------------------------------------------------------------
// helpers
// ---------------------------------------------------------------------------
__device__ __forceinline__ float bf2f(ushort_t u) {
    union { float f; uint32_t i; } v; v.i = ((uint32_t)u) << 16; return v.f;
}
__device__ __forceinline__ ushort_t f2bf(float f) {
    union { float f; uint32_t i; } v; v.f = f;
    uint32_t r = v.i + 0x7fffu + ((v.i >> 16) & 1u);
    return (ushort_t)(r >> 16);
}
// f32 -> OCP e4m3fn, RNE, saturating (HW-verified rounds 11/12)
__device__ __forceinline__ u8_t f2e4m3(float f) {
    union { float f; uint32_t u; } v; v.f = f;
    uint32_t s = (v.u >> 24) & 0x80u;
    float a = fabsf(f);
    if (a >= 448.f) return (u8_t)(s | 0x7Eu);
    union { float f; uint32_t u; } w; w.f = a;
    int E = (int)(w.u >> 23) - 127;
    if (E < -6) E = -6;
    union { uint32_t u; float f; } qs; qs.u = (uint32_t)(127 + 3 - E) << 23;
    int m = (int)rintf(a * qs.f);
    if (m >= 16) { m >>= 1; ++E; if (E > 8) return (u8_t)(s | 0x7Eu); }
    if (m >= 8)  return (u8_t)(s | ((uint32_t)(E + 7) << 3) | (uint32_t)(m - 8));
    return (u8_t)(s | (uint32_t)m);
}
// fq-major permutation within each 128-byte k-block: k -> blk | fq*32 | kk*8 | b
__device__ __forceinline__ int permk(int k) {
    const int w = k & 127;
    return (k - w) + ((w >> 3) & 3) * 32 + (w >> 5) * 8 + (w & 7);
}
__device__ __forceinline__ void gload_lds16(const void* g, void* l) {
    __builtin_amdgcn_global_load_lds(
        (const __attribute__((address_space(1))) uint32_t*)g,
        (__attribute__((address_space(3))) uint32_t*)l, 16, 0, 0);
}

// ---------------------------------------------------------------------------
// fp8 256x256 GEMM, BK=128 bytes — byte-clone of round-10 bf16 schedule
// (0 conflicts, counted vmcnt(6), one end-barrier/phase). Global data is
// fq-major-permuted per 128-B block, so fragment reads are 2x ds_read_b128
// per frag (granules 2fq, 2fq+1, XOR row&7) — conflict-free per the
// 16-lane-quarter model validated by the bf16 kernel's zero conflicts.
// MODE 0: C = fp8(relu(acc+bias)) stored PERMUTED (ready as next A). 
// MODE 1: MSE epilogue -> iimp_out (N=256 single col-block, pad cols zero).
// All pointers/strides in BYTES. K multiple of 256.
// ---------------------------------------------------------------------------
template<int MODE>
__global__ __launch_bounds__(512, 2)
void gemm8p_fp8(const u8_t* __restrict__ A, int lda,
                const u8_t* __restrict__ A2, int lda2, int ksplit,
                const u8_t* __restrict__ Bt,
                const float* __restrict__ bias,
                u8_t* __restrict__ C, int ldc, int K, int lgx, int rpx,
                float* __restrict__ iimp_out)
{
    __shared__ u8_t lds[131072];      // 2 bufs x (A 32768 + B 32768)

    const int tid  = threadIdx.x;
    const int w    = tid >> 6;
    const int lane = tid & 63;
    const int wm   = w >> 2;
    const int wn   = w & 3;
    const int fr   = lane & 15;
    const int fq   = lane >> 4;

    const int bid  = blockIdx.x;
    const int xcd  = bid & 7;
    const int slot = bid >> 3;
    const int x    = slot & ((1 << lgx) - 1);
    const int y    = xcd * rpx + (slot >> lgx);
    const size_t brow = (size_t)y * 256;
    const int    bcol = x * 256;

    const int NT = K >> 7;
    const int NI = NT >> 1;

    const int srl = tid >> 3;
    const int spg = tid & 7;

    f32x4 acc[8][4];
#pragma unroll
    for (int m = 0; m < 8; ++m)
#pragma unroll
        for (int n = 0; n < 4; ++n) acc[m][n] = (f32x4){0.f, 0.f, 0.f, 0.f};

    // staging bases — identical map to round-10 (16B granules, 8/row)
    const u8_t* aB1[4];
    const u8_t* aB2[4];
    const u8_t* bB[4];
    int ldsA[4], ldsB[4];
#pragma unroll
    for (int s = 0; s < 4; ++s) {
        const int rowA = (srl < 32) ? s * 32 + srl : 128 + s * 32 + (srl - 32);
        const int colA = ((spg ^ (rowA & 7)) << 4);
        aB1[s] = A  + (brow + rowA) * (size_t)lda  + colA;
        aB2[s] = A2 + (brow + rowA) * (size_t)lda2 + colA - ksplit;
        ldsA[s] = rowA * 128 + spg * 16;
        const int rowB = s * 64 + srl;
        const int colB = ((spg ^ (rowB & 7)) << 4);
        bB[s]   = Bt + (size_t)(bcol + rowB) * K + colB;
        ldsB[s] = 32768 + rowB * 128 + spg * 16;
    }

    auto stageA = [&](int T, int s, int bi) {
        const int k0 = T << 7;
        const u8_t* src = (k0 >= ksplit ? aB2[s] : aB1[s]) + k0;
        gload_lds16(src, &lds[(bi << 16) + ldsA[s]]);
    };
    auto stageB = [&](int T, int c, int bi) {
        gload_lds16(bB[c] + (T << 7), &lds[(bi << 16) + ldsB[c]]);
    };

    stageA(0, 0, 0); stageB(0, 0, 0);
    stageA(0, 1, 0); stageB(0, 1, 0);
    stageA(0, 2, 0); stageB(0, 2, 0);
    stageA(0, 3, 0); stageB(0, 3, 0);
    stageA(1, 0, 1); stageB(1, 0, 1);
    stageA(1, 1, 1); stageB(1, 1, 1);
    stageA(1, 2, 1); stageB(1, 2, 1);

    unsigned long long breg[4][4];

    for (int i = 0; i < NI; ++i) {
        const bool more = (i + 1 < NI);
#pragma unroll
        for (int h = 0; h < 2; ++h) {
            const int bufA = h << 16;
            const int bufB = (h << 16) + 32768;
#pragma unroll
            for (int q = 0; q < 4; ++q) {
                if (q == 0) {
                    if (h == 0 || more) asm volatile("s_waitcnt vmcnt(6)" ::: "memory");
                    else                asm volatile("s_waitcnt vmcnt(0)" ::: "memory");
                    __builtin_amdgcn_sched_barrier(0);
                    __builtin_amdgcn_s_barrier();
#pragma unroll
                    for (int n = 0; n < 4; ++n) {
                        const int row = wn * 64 + n * 16 + fr;
                        const int p0  = (2 * fq)     ^ (row & 7);
                        const int p1  = (2 * fq + 1) ^ (row & 7);
                        const u64x2 t0 = *(const u64x2*)&lds[bufB + row * 128 + p0 * 16];
                        const u64x2 t1 = *(const u64x2*)&lds[bufB + row * 128 + p1 * 16];
                        breg[n][0] = t0[0]; breg[n][1] = t0[1];
                        breg[n][2] = t1[0]; breg[n][3] = t1[1];
                    }
                }
                unsigned long long areg[2][4];
#pragma unroll
                for (int j = 0; j < 2; ++j) {
                    const int row = wm * 128 + (2 * q + j) * 16 + fr;
                    const int p0  = (2 * fq)     ^ (row & 7);
                    const int p1  = (2 * fq + 1) ^ (row & 7);
                    const u64x2 t0 = *(const u64x2*)&lds[bufA + row * 128 + p0 * 16];
                    const u64x2 t1 = *(const u64x2*)&lds[bufA + row * 128 + p1 * 16];
                    areg[j][0] = t0[0]; areg[j][1] = t0[1];
                    areg[j][2] = t1[0]; areg[j][3] = t1[1];
                }
                if (h == 0) {
                    if (q == 0)      { stageA(2*i+1, 3, 1); stageB(2*i+1, 3, 1); }
                    else if (more)   { stageA(2*i+2, q-1, 0); stageB(2*i+2, q-1, 0); }
                } else {
                    if (q == 0) { if (more) { stageA(2*i+2, 3, 0); stageB(2*i+2, 3, 0); } }
                    else        { if (more) { stageA(2*i+3, q-1, 1); stageB(2*i+3, q-1, 1); } }
                }
                __builtin_amdgcn_s_setprio(1);
#pragma unroll
                for (int j = 0; j < 2; ++j)
#pragma unroll
                    for (int n = 0; n < 4; ++n)
#pragma unroll
                        for (int kk = 0; kk < 4; ++kk)
                            acc[2*q+j][n] = __builtin_amdgcn_mfma_f32_16x16x32_fp8_fp8(
                                (long)areg[j][kk], (long)breg[n][kk], acc[2*q+j][n], 0, 0, 0);
                __builtin_amdgcn_s_setprio(0);
                __builtin_amdgcn_s_barrier();
            }
        }
    }

    if (MODE == 0) {
        // permuted fp8 store (output is next GEMM's A)
#pragma unroll
        for (int m = 0; m < 8; ++m) {
            const size_t rowb = brow + wm * 128 + m * 16 + fq * 4;
#pragma unroll
            for (int n = 0; n < 4; ++n) {
                const int col = bcol + wn * 64 + n * 16 + fr;
                const int pc  = permk(col);
                const float bv = bias[col];
#pragma unroll
                for (int r = 0; r < 4; ++r) {
                    const float v = fmaxf(acc[m][n][r] + bv, 0.f);
                    C[(rowb + r) * (size_t)ldc + pc] = f2e4m3(v);
                }
            }
        }
    } else {
        // MSE: per-row sumsq of (acc+bias) -> per-16-row softmax -> iimp
        float* rowsq = (float*)lds;
        if (tid < 256) rowsq[tid] = 0.f;
        __syncthreads();
#pragma unroll
        for (int m = 0; m < 8; ++m) {
#pragma unroll
            for (int r = 0; r < 4; ++r) {
                float s = 0.f;
#pragma unroll
                for (int n = 0; n < 4; ++n) {
                    const int col = wn * 64 + n * 16 + fr;
                    const float v = acc[m][n][r] + bias[col];
                    s += v * v;
                }
                s += __shfl_xor(s, 1);
                s += __shfl_xor(s, 2);
                s += __shfl_xor(s, 4);
                s += __shfl_xor(s, 8);
                if (fr == 0)
                    atomicAdd(&rowsq[wm * 128 + m * 16 + fq * 4 + r], s);
            }
        }
        __syncthreads();
        if (tid < 16) {
            const int rb = tid * 16;
            float mv[16], mx = -1e30f;
#pragma unroll
            for (int a = 0; a < 16; ++a) {
                mv[a] = rowsq[rb + a] * (1.f / 128.f);
                mx = fmaxf(mx, mv[a]);
            }
            float e[16], den = 0.f;
#pragma unroll
            for (int a = 0; a < 16; ++a) { e[a] = __expf(mv[a] - mx); den += e[a]; }
            const float inv = 1.f / den;
            const size_t b = brow / 16 + tid;
#pragma unroll
            for (int a = 0; a < 16; ++a) iimp_out[b * 16 + a] = e[a] * inv;
        }
    }
}

// ---------------------------------------------------------------------------
// bf16 8-phase 256x256 GEMM — exact round-10/13 kernel; FUSE_OUT for combine.
// ---------------------------------------------------------------------------
template<bool RELU, bool FUSE_OUT>
__global__ __launch_bounds__(512, 2)
void gemm8p(const ushort_t* __restrict__ A, int lda,
            const ushort_t* __restrict__ A2, int lda2, int ksplit,
            const ushort_t* __restrict__ Bt,
            const float* __restrict__ bias,
            ushort_t* __restrict__ C, int ldc, int K, int lgx, int rpx,
            const ushort_t* __restrict__ W2t, const float* __restrict__ b2)
{
    __shared__ ushort_t lds[65536];

    const int tid  = threadIdx.x;
    const int w    = tid >> 6;
    const int lane = tid & 63;
    const int wm   = w >> 2;
    const int wn   = w & 3;
    const int fr   = lane & 15;
    const int fq   = lane >> 4;

    const int bid  = blockIdx.x;
    const int xcd  = bid & 7;
    const int slot = bid >> 3;
    const int x    = slot & ((1 << lgx) - 1);
    const int y    = xcd * rpx + (slot >> lgx);
    const size_t brow = (size_t)y * 256;
    const int    bcol = x * 256;

    const int NT = K >> 6;
    const int NI = NT >> 1;

    const int srl = tid >> 3;
    const int spg = tid & 7;

    f32x4 acc[8][4];
#pragma unroll
    for (int m = 0; m < 8; ++m)
#pragma unroll
        for (int n = 0; n < 4; ++n) acc[m][n] = (f32x4){0.f, 0.f, 0.f, 0.f};

    const ushort_t* aB1[4];
    const ushort_t* aB2[4];
    const ushort_t* bB[4];
    int ldsA[4], ldsB[4];
#pragma unroll
    for (int s = 0; s < 4; ++s) {
        const int rowA = (srl < 32) ? s * 32 + srl : 128 + s * 32 + (srl - 32);
        const int colA = ((spg ^ (rowA & 7)) << 3);
        aB1[s] = A  + (brow + rowA) * (size_t)lda  + colA;
        aB2[s] = A2 + (brow + rowA) * (size_t)lda2 + colA - ksplit;
        ldsA[s] = rowA * 64 + spg * 8;
        const int rowB = s * 64 + srl;
        const int colB = ((spg ^ (rowB & 7)) << 3);
        bB[s]   = Bt + (size_t)(bcol + rowB) * K + colB;
        ldsB[s] = 16384 + rowB * 64 + spg * 8;
    }

    auto stageA = [&](int T, int s, int bi) {
        const int k0 = T << 6;
        const ushort_t* src = (k0 >= ksplit ? aB2[s] : aB1[s]) + k0;
        gload_lds16(src, &lds[(bi << 15) + ldsA[s]]);
    };
    auto stageB = [&](int T, int c, int bi) {
        gload_lds16(bB[c] + (T << 6), &lds[(bi << 15) + ldsB[c]]);
    };

    stageA(0, 0, 0); stageB(0, 0, 0);
    stageA(0, 1, 0); stageB(0, 1, 0);
    stageA(0, 2, 0); stageB(0, 2, 0);
    stageA(0, 3, 0); stageB(0, 3, 0);
    stageA(1, 0, 1); stageB(1, 0, 1);
    stageA(1, 1, 1); stageB(1, 1, 1);
    stageA(1, 2, 1); stageB(1, 2, 1);

    bf16x8 breg[4][2];

    for (int i = 0; i < NI; ++i) {
        const bool more = (i + 1 < NI);
#pragma unroll
        for (int h = 0; h < 2; ++h) {
            const int bufA = h << 15;
            const int bufB = (h << 15) + 16384;
#pragma unroll
            for (int q = 0; q < 4; ++q) {
                if (q == 0) {
                    if (h == 0 || more) asm volatile("s_waitcnt vmcnt(6)" ::: "memory");
                    else                asm volatile("s_waitcnt vmcnt(0)" ::: "memory");
                    __builtin_amdgcn_sched_barrier(0);
                    __builtin_amdgcn_s_barrier();
#pragma unroll
                    for (int n = 0; n < 4; ++n)
#pragma unroll
                        for (int kk = 0; kk < 2; ++kk) {
                            const int row = wn * 64 + n * 16 + fr;
                            const int gp  = ((kk * 4 + fq) ^ (row & 7)) << 3;
                            breg[n][kk] = *(const bf16x8*)&lds[bufB + row * 64 + gp];
                        }
                }
                bf16x8 areg[2][2];
#pragma unroll
                for (int j = 0; j < 2; ++j)
#pragma unroll
                    for (int kk = 0; kk < 2; ++kk) {
                        const int row = wm * 128 + (2 * q + j) * 16 + fr;
                        const int gp  = ((kk * 4 + fq) ^ (row & 7)) << 3;
                        areg[j][kk] = *(const bf16x8*)&lds[bufA + row * 64 + gp];
                    }
                if (h == 0) {
                    if (q == 0)      { stageA(2*i+1, 3, 1); stageB(2*i+1, 3, 1); }
                    else if (more)   { stageA(2*i+2, q-1, 0); stageB(2*i+2, q-1, 0); }
                } else {
                    if (q == 0) { if (more) { stageA(2*i+2, 3, 0); stageB(2*i+2, 3, 0); } }
                    else        { if (more) { stageA(2*i+3, q-1, 1); stageB(2*i+3, q-1, 1); } }
                }
                __builtin_amdgcn_s_setprio(1);
#pragma unroll
                for (int j = 0; j < 2; ++j)
#pragma unroll
                    for (int n = 0; n < 4; ++n)
#pragma unroll
                        for (int kk = 0; kk < 2; ++kk)
                            acc[2*q+j][n] = __builtin_amdgcn_mfma_f32_16x16x32_bf16(
                                areg[j][kk], breg[n][kk], acc[2*q+j][n], 0, 0, 0);
                __builtin_amdgcn_s_setprio(0);
                __builtin_amdgcn_s_barrier();
            }
        }
    }

    if (!FUSE_OUT) {
#pragma unroll
        for (int m = 0; m < 8; ++m) {
            const size_t rowb = brow + wm * 128 + m * 16 + fq * 4;
#pragma unroll
            for (int n = 0; n < 4; ++n) {
                const int col = bcol + wn * 64 + n * 16 + fr;
                const float bv = bias[col];
#pragma unroll
                for (int r = 0; r < 4; ++r) {
                    float v = acc[m][n][r] + bv;
                    if (RELU) v = fmaxf(v, 0.f);
                    C[(rowb + r) * (size_t)ldc + col] = f2bf(v);
                }
            }
        }
    } else {
#pragma unroll
        for (int m = 0; m < 8; ++m) {
            const int row = wm * 128 + m * 16 + fq * 4;
#pragma unroll
            for (int n = 0; n < 4; ++n) {
                const int col = wn * 64 + n * 16 + fr;
                const float bv = bias[col];
#pragma unroll
                for (int r = 0; r < 4; ++r) {
                    const float v = fmaxf(acc[m][n][r] + bv, 0.f);
                    const int rr = row + r;
                    const int g  = (col >> 3) ^ (rr & 7);
                    lds[rr * 256 + g * 8 + (col & 7)] = f2bf(v);
                }
            }
        }
        bf16x8 w2f[4][8];
#pragma unroll
        for (int n2 = 0; n2 < 4; ++n2)
#pragma unroll
            for (int kk = 0; kk < 8; ++kk)
                w2f[n2][kk] = *(const bf16x8*)&W2t[(n2 * 16 + fr) * 256 + kk * 32 + fq * 8];
        __syncthreads();
        f32x4 acc2[2][4];
#pragma unroll
        for (int m2 = 0; m2 < 2; ++m2)
#pragma unroll
            for (int n2 = 0; n2 < 4; ++n2) acc2[m2][n2] = (f32x4){0.f, 0.f, 0.f, 0.f};
#pragma unroll
        for (int kk = 0; kk < 8; ++kk) {
#pragma unroll
            for (int m2 = 0; m2 < 2; ++m2) {
                const int row = w * 32 + m2 * 16 + fr;
                const int g   = (kk * 4 + fq) ^ (row & 7);
                const bf16x8 af = *(const bf16x8*)&lds[row * 256 + g * 8];
#pragma unroll
                for (int n2 = 0; n2 < 4; ++n2)
                    acc2[m2][n2] = __builtin_amdgcn_mfma_f32_16x16x32_bf16(
                        af, w2f[n2][kk], acc2[m2][n2], 0, 0, 0);
            }
        }
        float* outp = (float*)C;
#pragma unroll
        for (int m2 = 0; m2 < 2; ++m2) {
            const size_t rowb = brow + w * 32 + m2 * 16 + fq * 4;
#pragma unroll
            for (int n2 = 0; n2 < 4; ++n2) {
                const int col = n2 * 16 + fr;
                const float bv = b2[col];
#pragma unroll
                for (int r = 0; r < 4; ++r)
                    outp[(rowb + r) * 64 + col] = acc2[m2][n2][r] + bv;
            }
        }
    }
}

// ---------------------------------------------------------------------------
// bf16 128x128 GEMM (proven) — kvq only.
// ---------------------------------------------------------------------------
__global__ __launch_bounds__(256)
void gemm_mfma(const ushort_t* __restrict__ A, int lda,
               const ushort_t* __restrict__ Bt,
               const float* __restrict__ bias,
               ushort_t* __restrict__ C, int ldc, int N, int K, int lgx)
{
    __shared__ ushort_t As[2][128 * 64];
    __shared__ ushort_t Bs[2][128 * 64];

    const int tid  = threadIdx.x;
    const int w    = tid >> 6;
    const int lane = tid & 63;
    const int wm   = w >> 1;
    const int wn   = w & 1;

    const int bid  = blockIdx.x;
    const int xcd  = bid & 7;
    const int slot = bid >> 3;
    const int x    = slot & ((1 << lgx) - 1);
    const int y    = xcd * 128 + (slot >> lgx);
    const size_t brow = (size_t)y * 128;
    const int    bcol = x * 128;

    const int fr   = lane & 15;
    const int fq   = lane >> 4;
    const int srow = lane >> 3;
    const int scol = (lane & 7) << 3;

    f32x4 acc[4][4];
#pragma unroll
    for (int i = 0; i < 4; ++i)
#pragma unroll
        for (int j = 0; j < 4; ++j) acc[i][j] = (f32x4){0.f, 0.f, 0.f, 0.f};

    const int NT = K >> 6;

    auto stage = [&](int buf, int k0) {
#pragma unroll
        for (int i = 0; i < 4; ++i) {
            const int c = (w << 2) + i;
            const int r = (c << 3) + srow;
            gload_lds16(A + (brow + r) * (size_t)lda + k0 + scol,
                        &As[buf][(c << 9) + lane * 8]);
            gload_lds16(Bt + (size_t)(bcol + r) * K + k0 + scol,
                        &Bs[buf][(c << 9) + lane * 8]);
        }
    };

    stage(0, 0);
    __syncthreads();

    for (int t = 0; t < NT; ++t) {
        const int cur = t & 1;
        if (t + 1 < NT) stage(cur ^ 1, (t + 1) << 6);
#pragma unroll
        for (int kk = 0; kk < 2; ++kk) {
            bf16x8 a[4], b[4];
#pragma unroll
            for (int f = 0; f < 4; ++f) {
                a[f] = *(const bf16x8*)&As[cur][(wm * 64 + f * 16 + fr) * 64 + kk * 32 + fq * 8];
                b[f] = *(const bf16x8*)&Bs[cur][(wn * 64 + f * 16 + fr) * 64 + kk * 32 + fq * 8];
            }
#pragma unroll
            for (int fm = 0; fm < 4; ++fm)
#pragma unroll
                for (int fn = 0; fn < 4; ++fn)
                    acc[fm][fn] = __builtin_amdgcn_mfma_f32_16x16x32_bf16(
                        a[fm], b[fn], acc[fm][fn], 0, 0, 0);
        }
        __syncthreads();
    }

#pragma unroll
    for (int fm = 0; fm < 4; ++fm) {
        const size_t rowb = brow + wm * 64 + fm * 16 + fq * 4;
#pragma unroll
        for (int fn = 0; fn < 4; ++fn) {
            const int col = bcol + wn * 64 + fn * 16 + fr;
            if (col < N) {
                const float bv = bias[col];
#pragma unroll
                for (int r = 0; r < 4; ++r)
                    C[(rowb + r) * (size_t)ldc + col] = f2bf(acc[fm][fn][r] + bv);
            }
        }
    }
}

// ---------------------------------------------------------------------------
// ONE merged prep kernel (fp8 permuted + bf16 transposes + bias packs).
// ---------------------------------------------------------------------------
__device__ __forceinline__ void dev_tr_bf16(const float* W, ushort_t* Wt,
                                            int K, int N, int Npad, int idx)
{
    if (idx >= Npad * K) return;
    int n = idx / K, k = idx - n * K;
    float v = (n < N) ? W[(size_t)k * N + n] : 0.f;
    Wt[idx] = f2bf(v);
}
__device__ __forceinline__ void dev_tr_fp8(const float* W, u8_t* Wt,
                                           int K, int N, int idx)
{
    if (idx >= N * K) return;
    int n = idx / K, k = idx - n * K;
    Wt[(size_t)n * K + permk(k)] = f2e4m3(W[(size_t)k * N + n]);
}
__device__ __forceinline__ void dev_tr_fp8_k(const float* W, u8_t* Wt,
                                             int Ksrc, int N, int ldk,
                                             int kOff, float sign, int idx)
{
    if (idx >= N * Ksrc) return;
    int n = idx / Ksrc, k = idx - n * Ksrc;
    Wt[(size_t)n * ldk + permk(kOff + k)] = f2e4m3(sign * W[(size_t)k * N + n]);
}

__global__ __launch_bounds__(256)
void prep_all(const float* __restrict__ Wt1, const float* __restrict__ Wp1,
              const float* __restrict__ Wp2, const float* __restrict__ Wt2,
              const float* __restrict__ Wp3, const float* __restrict__ Wk,
              const float* __restrict__ Wq,  const float* __restrict__ Wv,
              const float* __restrict__ Wc,  const float* __restrict__ W2,
              const float* __restrict__ bt1, const float* __restrict__ bp1,
              const float* __restrict__ bk,  const float* __restrict__ bq,
              const float* __restrict__ bv,  const float* __restrict__ bt2,
              const float* __restrict__ bp3,
              u8_t* __restrict__ Bg1, u8_t* __restrict__ Wp2t8,
              u8_t* __restrict__ Dt8, ushort_t* __restrict__ Wkvq,
              ushort_t* __restrict__ Wct, ushort_t* __restrict__ W2t,
              float* __restrict__ g1bias, float* __restrict__ pbias,
              float* __restrict__ cbias)
{
    const int b = blockIdx.x;
    const int t = threadIdx.x;
    if (b < 1024)        dev_tr_fp8(Wt1, Bg1,             512, 512, (b - 0)    * 256 + t);
    else if (b < 2048)   dev_tr_fp8(Wp1, Bg1 + 512 * 512, 512, 512, (b - 1024) * 256 + t);
    else if (b < 3072)   dev_tr_fp8(Wp2, Wp2t8,           512, 512, (b - 2048) * 256 + t);
    else if (b < 3328)   dev_tr_fp8_k(Wt2, Dt8, 512, 128, 1024, 0,    1.f, (b - 3072) * 256 + t);
    else if (b < 3584)   dev_tr_fp8_k(Wp3, Dt8, 512, 128, 1024, 512, -1.f, (b - 3328) * 256 + t);
    else if (b < 4096) { // Dt8 zero pad rows 128..255 (131072 bytes)
        int i = (b - 3584) * 256 + t;
        Dt8[128 * 1024 + i] = 0;
    }
    else if (b < 4128)   dev_tr_bf16(Wk, Wkvq + 0 * 256,   256, 32, 32,   (b - 4096) * 256 + t);
    else if (b < 4160)   dev_tr_bf16(Wq, Wkvq + 32 * 256,  256, 32, 32,   (b - 4128) * 256 + t);
    else if (b < 4288)   dev_tr_bf16(Wv, Wkvq + 64 * 256,  256, 128, 128, (b - 4160) * 256 + t);
    else if (b < 4352)   dev_tr_bf16(Wk, Wkvq + 192 * 256, 256, 0, 64,    (b - 4288) * 256 + t); // zero pad
    else if (b < 4736)   dev_tr_bf16(Wc, Wct, 384, 256, 256, (b - 4352) * 256 + t);
    else if (b < 4864)   dev_tr_bf16(W2, W2t, 256, 64, 128,  (b - 4736) * 256 + t);
    else if (b < 4868) { // g1bias = [bt1 | bp1]
        int j = (b - 4864) * 256 + t;
        if (j < 512) g1bias[j] = bt1[j];
        else         g1bias[j] = bp1[j - 512];
    } else if (b == 4868) { // pbias
        float v = 0.f;
        if      (t < 32)  v = bk[t];
        else if (t < 64)  v = bq[t - 32];
        else if (t < 192) v = bv[t - 64];
        pbias[t] = v;
    } else {              // cbias (256: pad zero)
        cbias[t] = (t < 128) ? (bt2[t] - bp3[t]) : 0.f;
    }
}

// merged conversions: b<65536: x -> fp8 permuted; else hidden -> bf16 linear
__global__ __launch_bounds__(256)
void conv_all(const float* __restrict__ x, const float* __restrict__ hidden,
              u8_t* __restrict__ xb8, ushort_t* __restrict__ hiddenb)
{
    const int b = blockIdx.x;
    const int t = threadIdx.x;
    if (b < 65536) {
        const size_t q = (size_t)b * 256 + t;        // quad index
        const float4 v = ((const float4*)x)[q];
        const size_t row = q >> 7;                   // 128 quads per 512-col row
        const int k = (int)(q & 127) << 2;
        uint32_t pk = (uint32_t)f2e4m3(v.x) | ((uint32_t)f2e4m3(v.y) << 8) |
                      ((uint32_t)f2e4m3(v.z) << 16) | ((uint32_t)f2e4m3(v.w) << 24);
        *(uint32_t*)&xb8[row * 512 + permk(k)] = pk;
    } else {
        const size_t q = (size_t)(b - 65536) * 256 + t;
        const float4 v = ((const float4*)hidden)[q];
        ushort_t* d = hiddenb + q * 4;
        d[0] = f2bf(v.x); d[1] = f2bf(v.y); d[2] = f2bf(v.z); d[3] = f2bf(v.w);
    }
}

// ---------------------------------------------------------------------------
// attention: kvq packed [BA][192] bf16; vectorized staging (round-13).
// ---------------------------------------------------------------------------
__global__ __launch_bounds__(256)
void attn_apply(const ushort_t* __restrict__ kvq, const float* __restrict__ Wa,
                const float* __restrict__ ba, const float* __restrict__ iimp,
                ushort_t* __restrict__ applied)
{
    const int b = blockIdx.x, t = threadIdx.x;
    __shared__ float klds[512], qlds[512];
    __shared__ ushort_t vlds[2048];
    __shared__ float part[16][17];
    __shared__ float kp[16];
    __shared__ float attn[16][17];

    {
        const int i = t * 2;
        const int a = i >> 5, c = i & 31;
        const size_t base = ((size_t)b * AA + a) * 192;
        const uint32_t uk = *(const uint32_t*)(kvq + base + c);
        const uint32_t uq = *(const uint32_t*)(kvq + base + 32 + c);
        klds[i]     = bf2f((ushort_t)(uk & 0xffff));
        klds[i + 1] = bf2f((ushort_t)(uk >> 16));
        qlds[i]     = bf2f((ushort_t)(uq & 0xffff));
        qlds[i + 1] = bf2f((ushort_t)(uq >> 16));
    }
    {
        const int j = t >> 4, e = t & 15;
        const uint4 v = *(const uint4*)(kvq + ((size_t)b * AA + j) * 192 + 64 + e * 8);
        *(uint4*)&vlds[j * 128 + e * 8] = v;
    }
    __syncthreads();

    {
        int j = t & 15, seg = t >> 4;
        float s = 0.f;
        for (int c = seg * 32; c < seg * 32 + 32; ++c)
            s += klds[c] * Wa[(32 + c) * 16 + j];
        part[j][seg] = s;
    }
    __syncthreads();
    if (t < 16) {
        float s = 0.f;
#pragma unroll
        for (int seg = 0; seg < 16; ++seg) s += part[t][seg];
        kp[t] = s;
    }
    __syncthreads();

    {
        int i = t >> 4, j = t & 15;
        float s = 0.f;
#pragma unroll
        for (int q = 0; q < 32; ++q) s += qlds[i * 32 + q] * Wa[q * 16 + j];
        attn[i][j] = s + kp[j] + ba[j];
    }
    __syncthreads();
    if (t < 16) {
        float mx = -1e30f;
#pragma unroll
        for (int j = 0; j < 16; ++j) mx = fmaxf(mx, attn[t][j]);
        float e[16], den = 0.f;
#pragma unroll
        for (int j = 0; j < 16; ++j) { e[j] = __expf(attn[t][j] - mx); den += e[j]; }
        float inv = 1.f / den;
#pragma unroll
        for (int j = 0; j < 16; ++j)
            attn[t][j] = e[j] * inv + 0.5f * iimp[b * 16 + j];
    }
    __syncthreads();

    for (int o = t; o < 2048; o += 256) {
        int i = o >> 7, v = o & 127;
        float s = 0.f;
#pragma unroll
        for (int j = 0; j < 16; ++j) s += attn[i][j] * bf2f(vlds[j * 128 + v]);
        applied[((size_t)b * AA + i) * 128 + v] = f2bf(s);
    }
}

// ---------------------------------------------------------------------------
// launch
// ---------------------------------------------------------------------------
extern "C" void kernel_launch(void* const* d_in, const int* in_sizes, int n_in,
                              void* d_out, int out_size, void* d_ws, size_t ws_size,
                              hipStream_t stream)
{
    const float* x      = (const float*)d_in[0];
    const float* hidden = (const float*)d_in[1];
    const float* Wk  = (const float*)d_in[2];
    const float* bk  = (const float*)d_in[3];
    const float* Wv  = (const float*)d_in[4];
    const float* bv  = (const float*)d_in[5];
    const float* Wq  = (const float*)d_in[6];
    const float* bq  = (const float*)d_in[7];
    const float* Wa  = (const float*)d_in[8];
    const float* ba  = (const float*)d_in[9];
    const float* Wt1 = (const float*)d_in[10];
    const float* bt1 = (const float*)d_in[11];
    const float* Wt2 = (const float*)d_in[12];
    const float* bt2 = (const float*)d_in[13];
    const float* Wp1 = (const float*)d_in[14];
    const float* bp1 = (const float*)d_in[15];
    const float* Wp2 = (const float*)d_in[16];
    const float* bp2 = (const float*)d_in[17];
    const float* Wp3 = (const float*)d_in[18];
    const float* bp3 = (const float*)d_in[19];
    const float* Wc  = (const float*)d_in[20];
    const float* bc  = (const float*)d_in[21];
    const float* W2  = (const float*)d_in[22];
    const float* b2  = (const float*)d_in[23];

    float* out = (float*)d_out;
    u8_t*  ws8 = (u8_t*)d_ws;

    // ---- workspace (bytes) -------------------------------------------------
    u8_t* xb8  = ws8;                          // [BA*512]  x fp8 (permuted)
    u8_t* ht8  = xb8 + (size_t)BA * 512;       // [BA*1024] [h_t|h_p1] fp8 perm
    u8_t* hp8  = ht8 + (size_t)BA * 1024;      // [BA*512]  h_p2 fp8 perm
    u8_t* hidb = hp8 + (size_t)BA * 512;       // [BA*512]  hidden bf16 (own)
    u8_t* WT   = hidb + (size_t)BA * 512;
    ushort_t* hiddenb = (ushort_t*)hidb;
    ushort_t* kvq     = (ushort_t*)xb8;        // BA*384 B  (x dead)
    ushort_t* applied = (ushort_t*)ht8;        // BA*256 B  (ht8 dead after diff)

    u8_t* Bg1   = WT;                          // 1024*512 fp8
    u8_t* Wp2t8 = Bg1 + 1024 * 512;            // 512*512 fp8
    u8_t* Dt8   = Wp2t8 + 512 * 512;           // 256*1024 fp8 (pad rows zero)
    ushort_t* Wkvq = (ushort_t*)(Dt8 + 256 * 1024);  // 256*256 bf16
    ushort_t* Wct  = Wkvq + 256 * 256;         // 256*384 bf16
    ushort_t* W2t  = Wct  + 256 * 384;         // 128*256 bf16
    float* g1bias = (float*)(W2t + 128 * 256);
    float* pbias  = g1bias + 1024;
    float* cbias  = pbias + 256;
    float* iimp   = cbias + 256;               // BB*AA floats

    const dim3 blk(256);
    const int BIG = 1 << 30;

    // ---- prep + conversions (2 dispatches) --------------------------------
    prep_all<<<4870, blk, 0, stream>>>(
        Wt1, Wp1, Wp2, Wt2, Wp3, Wk, Wq, Wv, Wc, W2,
        bt1, bp1, bk, bq, bv, bt2, bp3,
        Bg1, Wp2t8, Dt8, Wkvq, Wct, W2t, g1bias, pbias, cbias);
    conv_all<<<98304, blk, 0, stream>>>(x, hidden, xb8, hiddenb);

    // ---- phase 1: predictor branch (fp8, permuted) -------------------------
    // [h_t | h_p1] = relu(x @ [Wt1|Wp1] + [bt1|bp1])
    gemm8p_fp8<0><<<2048, 512, 0, stream>>>(
        xb8, 512, xb8, 512, BIG, Bg1, g1bias, ht8, 1024, 512, 2, 64, nullptr);
    // h_p2 = relu(h_p1 @ Wp2 + bp2)
    gemm8p_fp8<0><<<1024, 512, 0, stream>>>(
        ht8 + 512, 1024, ht8 + 512, 1024, BIG, Wp2t8, bp2, hp8, 512, 512, 1, 64, nullptr);
    // diff = [h_t|h_p2]@[Wt2;-Wp3]+cbias -> rowsq -> softmax -> iimp
    gemm8p_fp8<1><<<512, 512, 0, stream>>>(
        ht8, 1024, hp8, 512, 512, Dt8, cbias, nullptr, 0, 1024, 0, 64, iimp);

    // ---- phase 2: communicate (bf16) ---------------------------------------
    gemm_mfma<<<2048, blk, 0, stream>>>(
        hiddenb, 256, Wkvq, pbias, kvq, 192, 192, 256, 1);
    attn_apply<<<BB, blk, 0, stream>>>(kvq, Wa, ba, iimp, applied);

    // ---- phase 3: combine + output head (fully fused, bf16) ----------------
    gemm8p<true, true><<<512, 512, 0, stream>>>(
        applied, 128, hiddenb, 256, 128, Wct, bc, (ushort_t*)out, 64, 384, 0, 64, W2t, b2);
}

// Round 15
// 562.532 us; speedup vs baseline: 1.2571x; 1.2571x over previous
//
#include <hip/hip_runtime.h>
#include <cstddef>
#include <cstdint>

typedef unsigned short ushort_t;
typedef __attribute__((ext_vector_type(4))) float f32x4;
typedef __attribute__((ext_vector_type(8))) short bf16x8;

#define BB   8192
#define AA   16
#define BA   131072

// ---------------------------------------------------------------------------
// bf16 helpers
// ---------------------------------------------------------------------------
__device__ __forceinline__ float bf2f(ushort_t u) {
    union { float f; uint32_t i; } v; v.i = ((uint32_t)u) << 16; return v.f;
}
__device__ __forceinline__ ushort_t f2bf(float f) {
    union { float f; uint32_t i; } v; v.f = f;
    uint32_t r = v.i + 0x7fffu + ((v.i >> 16) & 1u);
    return (ushort_t)(r >> 16);
}
__device__ __forceinline__ void gload_lds16(const void* g, void* l) {
    __builtin_amdgcn_global_load_lds(
        (const __attribute__((address_space(1))) uint32_t*)g,
        (__attribute__((address_space(3))) uint32_t*)l, 16, 0, 0);
}

// ---------------------------------------------------------------------------
// bf16 8-phase 256x256 GEMM — EXACT round-10/13 kernel (best measured:
// 0 bank conflicts, counted vmcnt(6), one end-barrier/phase, precomputed
// staging bases). FUSE_OUT: combine+output-head fusion (round-9-proven).
// ---------------------------------------------------------------------------
template<bool RELU, bool FUSE_OUT>
__global__ __launch_bounds__(512, 2)
void gemm8p(const ushort_t* __restrict__ A, int lda,
            const ushort_t* __restrict__ A2, int lda2, int ksplit,
            const ushort_t* __restrict__ Bt,
            const float* __restrict__ bias,
            ushort_t* __restrict__ C, int ldc, int K, int lgx, int rpx,
            const ushort_t* __restrict__ W2t, const float* __restrict__ b2)
{
    __shared__ ushort_t lds[65536];

    const int tid  = threadIdx.x;
    const int w    = tid >> 6;
    const int lane = tid & 63;
    const int wm   = w >> 2;
    const int wn   = w & 3;
    const int fr   = lane & 15;
    const int fq   = lane >> 4;

    const int bid  = blockIdx.x;
    const int xcd  = bid & 7;
    const int slot = bid >> 3;
    const int x    = slot & ((1 << lgx) - 1);
    const int y    = xcd * rpx + (slot >> lgx);
    const size_t brow = (size_t)y * 256;
    const int    bcol = x * 256;

    const int NT = K >> 6;
    const int NI = NT >> 1;

    const int srl = tid >> 3;
    const int spg = tid & 7;

    f32x4 acc[8][4];
#pragma unroll
    for (int m = 0; m < 8; ++m)
#pragma unroll
        for (int n = 0; n < 4; ++n) acc[m][n] = (f32x4){0.f, 0.f, 0.f, 0.f};

    const ushort_t* aB1[4];
    const ushort_t* aB2[4];
    const ushort_t* bB[4];
    int ldsA[4], ldsB[4];
#pragma unroll
    for (int s = 0; s < 4; ++s) {
        const int rowA = (srl < 32) ? s * 32 + srl : 128 + s * 32 + (srl - 32);
        const int colA = ((spg ^ (rowA & 7)) << 3);
        aB1[s] = A  + (brow + rowA) * (size_t)lda  + colA;
        aB2[s] = A2 + (brow + rowA) * (size_t)lda2 + colA - ksplit;
        ldsA[s] = rowA * 64 + spg * 8;
        const int rowB = s * 64 + srl;
        const int colB = ((spg ^ (rowB & 7)) << 3);
        bB[s]   = Bt + (size_t)(bcol + rowB) * K + colB;
        ldsB[s] = 16384 + rowB * 64 + spg * 8;
    }

    auto stageA = [&](int T, int s, int bi) {
        const int k0 = T << 6;
        const ushort_t* src = (k0 >= ksplit ? aB2[s] : aB1[s]) + k0;
        gload_lds16(src, &lds[(bi << 15) + ldsA[s]]);
    };
    auto stageB = [&](int T, int c, int bi) {
        gload_lds16(bB[c] + (T << 6), &lds[(bi << 15) + ldsB[c]]);
    };

    stageA(0, 0, 0); stageB(0, 0, 0);
    stageA(0, 1, 0); stageB(0, 1, 0);
    stageA(0, 2, 0); stageB(0, 2, 0);
    stageA(0, 3, 0); stageB(0, 3, 0);
    stageA(1, 0, 1); stageB(1, 0, 1);
    stageA(1, 1, 1); stageB(1, 1, 1);
    stageA(1, 2, 1); stageB(1, 2, 1);

    bf16x8 breg[4][2];

    for (int i = 0; i < NI; ++i) {
        const bool more = (i + 1 < NI);
#pragma unroll
        for (int h = 0; h < 2; ++h) {
            const int bufA = h << 15;
            const int bufB = (h << 15) + 16384;
#pragma unroll
            for (int q = 0; q < 4; ++q) {
                if (q == 0) {
                    if (h == 0 || more) asm volatile("s_waitcnt vmcnt(6)" ::: "memory");
                    else                asm volatile("s_waitcnt vmcnt(0)" ::: "memory");
                    __builtin_amdgcn_sched_barrier(0);
                    __builtin_amdgcn_s_barrier();
#pragma unroll
                    for (int n = 0; n < 4; ++n)
#pragma unroll
                        for (int kk = 0; kk < 2; ++kk) {
                            const int row = wn * 64 + n * 16 + fr;
                            const int gp  = ((kk * 4 + fq) ^ (row & 7)) << 3;
                            breg[n][kk] = *(const bf16x8*)&lds[bufB + row * 64 + gp];
                        }
                }
                bf16x8 areg[2][2];
#pragma unroll
                for (int j = 0; j < 2; ++j)
#pragma unroll
                    for (int kk = 0; kk < 2; ++kk) {
                        const int row = wm * 128 + (2 * q + j) * 16 + fr;
                        const int gp  = ((kk * 4 + fq) ^ (row & 7)) << 3;
                        areg[j][kk] = *(const bf16x8*)&lds[bufA + row * 64 + gp];
                    }
                if (h == 0) {
                    if (q == 0)      { stageA(2*i+1, 3, 1); stageB(2*i+1, 3, 1); }
                    else if (more)   { stageA(2*i+2, q-1, 0); stageB(2*i+2, q-1, 0); }
                } else {
                    if (q == 0) { if (more) { stageA(2*i+2, 3, 0); stageB(2*i+2, 3, 0); } }
                    else        { if (more) { stageA(2*i+3, q-1, 1); stageB(2*i+3, q-1, 1); } }
                }
                __builtin_amdgcn_s_setprio(1);
#pragma unroll
                for (int j = 0; j < 2; ++j)
#pragma unroll
                    for (int n = 0; n < 4; ++n)
#pragma unroll
                        for (int kk = 0; kk < 2; ++kk)
                            acc[2*q+j][n] = __builtin_amdgcn_mfma_f32_16x16x32_bf16(
                                areg[j][kk], breg[n][kk], acc[2*q+j][n], 0, 0, 0);
                __builtin_amdgcn_s_setprio(0);
                __builtin_amdgcn_s_barrier();
            }
        }
    }

    if (!FUSE_OUT) {
#pragma unroll
        for (int m = 0; m < 8; ++m) {
            const size_t rowb = brow + wm * 128 + m * 16 + fq * 4;
#pragma unroll
            for (int n = 0; n < 4; ++n) {
                const int col = bcol + wn * 64 + n * 16 + fr;
                const float bv = bias[col];
#pragma unroll
                for (int r = 0; r < 4; ++r) {
                    float v = acc[m][n][r] + bv;
                    if (RELU) v = fmaxf(v, 0.f);
                    C[(rowb + r) * (size_t)ldc + col] = f2bf(v);
                }
            }
        }
    } else {
#pragma unroll
        for (int m = 0; m < 8; ++m) {
            const int row = wm * 128 + m * 16 + fq * 4;
#pragma unroll
            for (int n = 0; n < 4; ++n) {
                const int col = wn * 64 + n * 16 + fr;
                const float bv = bias[col];
#pragma unroll
                for (int r = 0; r < 4; ++r) {
                    const float v = fmaxf(acc[m][n][r] + bv, 0.f);
                    const int rr = row + r;
                    const int g  = (col >> 3) ^ (rr & 7);
                    lds[rr * 256 + g * 8 + (col & 7)] = f2bf(v);
                }
            }
        }
        bf16x8 w2f[4][8];
#pragma unroll
        for (int n2 = 0; n2 < 4; ++n2)
#pragma unroll
            for (int kk = 0; kk < 8; ++kk)
                w2f[n2][kk] = *(const bf16x8*)&W2t[(n2 * 16 + fr) * 256 + kk * 32 + fq * 8];
        __syncthreads();
        f32x4 acc2[2][4];
#pragma unroll
        for (int m2 = 0; m2 < 2; ++m2)
#pragma unroll
            for (int n2 = 0; n2 < 4; ++n2) acc2[m2][n2] = (f32x4){0.f, 0.f, 0.f, 0.f};
#pragma unroll
        for (int kk = 0; kk < 8; ++kk) {
#pragma unroll
            for (int m2 = 0; m2 < 2; ++m2) {
                const int row = w * 32 + m2 * 16 + fr;
                const int g   = (kk * 4 + fq) ^ (row & 7);
                const bf16x8 af = *(const bf16x8*)&lds[row * 256 + g * 8];
#pragma unroll
                for (int n2 = 0; n2 < 4; ++n2)
                    acc2[m2][n2] = __builtin_amdgcn_mfma_f32_16x16x32_bf16(
                        af, w2f[n2][kk], acc2[m2][n2], 0, 0, 0);
            }
        }
        float* outp = (float*)C;
#pragma unroll
        for (int m2 = 0; m2 < 2; ++m2) {
            const size_t rowb = brow + w * 32 + m2 * 16 + fq * 4;
#pragma unroll
            for (int n2 = 0; n2 < 4; ++n2) {
                const int col = n2 * 16 + fr;
                const float bv = b2[col];
#pragma unroll
                for (int r = 0; r < 4; ++r)
                    outp[(rowb + r) * 64 + col] = acc2[m2][n2][r] + bv;
            }
        }
    }
}

// ---------------------------------------------------------------------------
// 128x128 MFMA GEMM (proven). MSE=true: fused MSE+softmax -> iimp_out.
// ---------------------------------------------------------------------------
template<bool OBF16, bool RELU, bool MSE>
__global__ __launch_bounds__(256)
void gemm_mfma(const ushort_t* __restrict__ A, int lda,
               const ushort_t* __restrict__ A2, int lda2, int ksplit,
               const ushort_t* __restrict__ Bt,
               const float* __restrict__ bias,
               void* __restrict__ C, int ldc, int N, int K, int lgx,
               float* __restrict__ iimp_out)
{
    __shared__ ushort_t As[2][128 * 64];
    __shared__ ushort_t Bs[2][128 * 64];

    const int tid  = threadIdx.x;
    const int w    = tid >> 6;
    const int lane = tid & 63;
    const int wm   = w >> 1;
    const int wn   = w & 1;

    const int bid  = blockIdx.x;
    const int xcd  = bid & 7;
    const int slot = bid >> 3;
    const int x    = slot & ((1 << lgx) - 1);
    const int y    = xcd * 128 + (slot >> lgx);
    const size_t brow = (size_t)y * 128;
    const int    bcol = x * 128;

    const int fr   = lane & 15;
    const int fq   = lane >> 4;
    const int srow = lane >> 3;
    const int scol = (lane & 7) << 3;

    f32x4 acc[4][4];
#pragma unroll
    for (int i = 0; i < 4; ++i)
#pragma unroll
        for (int j = 0; j < 4; ++j) acc[i][j] = (f32x4){0.f, 0.f, 0.f, 0.f};

    const int NT = K >> 6;

    auto stage = [&](int buf, int k0) {
#pragma unroll
        for (int i = 0; i < 4; ++i) {
            const int c = (w << 2) + i;
            const int r = (c << 3) + srow;
            const ushort_t* asrc;
            if (k0 >= ksplit)
                asrc = A2 + (brow + r) * (size_t)lda2 + (k0 - ksplit) + scol;
            else
                asrc = A  + (brow + r) * (size_t)lda  + k0 + scol;
            gload_lds16(asrc, &As[buf][(c << 9) + lane * 8]);
            gload_lds16(Bt + (size_t)(bcol + r) * K + k0 + scol,
                        &Bs[buf][(c << 9) + lane * 8]);
        }
    };

    stage(0, 0);
    __syncthreads();

    for (int t = 0; t < NT; ++t) {
        const int cur = t & 1;
        if (t + 1 < NT) stage(cur ^ 1, (t + 1) << 6);
#pragma unroll
        for (int kk = 0; kk < 2; ++kk) {
            bf16x8 a[4], b[4];
#pragma unroll
            for (int f = 0; f < 4; ++f) {
                a[f] = *(const bf16x8*)&As[cur][(wm * 64 + f * 16 + fr) * 64 + kk * 32 + fq * 8];
                b[f] = *(const bf16x8*)&Bs[cur][(wn * 64 + f * 16 + fr) * 64 + kk * 32 + fq * 8];
            }
#pragma unroll
            for (int fm = 0; fm < 4; ++fm)
#pragma unroll
                for (int fn = 0; fn < 4; ++fn)
                    acc[fm][fn] = __builtin_amdgcn_mfma_f32_16x16x32_bf16(
                        a[fm], b[fn], acc[fm][fn], 0, 0, 0);
        }
        __syncthreads();
    }

    if (MSE) {
        float* rowsq = (float*)As;
        if (tid < 128) rowsq[tid] = 0.f;
        __syncthreads();
#pragma unroll
        for (int fm = 0; fm < 4; ++fm) {
#pragma unroll
            for (int r = 0; r < 4; ++r) {
                float s = 0.f;
#pragma unroll
                for (int fn = 0; fn < 4; ++fn) {
                    const int col = wn * 64 + fn * 16 + fr;
                    const float v = acc[fm][fn][r] + bias[col];
                    s += v * v;
                }
                s += __shfl_xor(s, 1);
                s += __shfl_xor(s, 2);
                s += __shfl_xor(s, 4);
                s += __shfl_xor(s, 8);
                if (fr == 0)
                    atomicAdd(&rowsq[wm * 64 + fm * 16 + fq * 4 + r], s);
            }
        }
        __syncthreads();
        if (tid < 8) {
            const int rb = tid * 16;
            float mv[16], mx = -1e30f;
#pragma unroll
            for (int a = 0; a < 16; ++a) {
                mv[a] = rowsq[rb + a] * (1.f / 128.f);
                mx = fmaxf(mx, mv[a]);
            }
            float e[16], den = 0.f;
#pragma unroll
            for (int a = 0; a < 16; ++a) { e[a] = __expf(mv[a] - mx); den += e[a]; }
            const float inv = 1.f / den;
            const size_t b = brow / 16 + tid;
#pragma unroll
            for (int a = 0; a < 16; ++a) iimp_out[b * 16 + a] = e[a] * inv;
        }
        return;
    }

#pragma unroll
    for (int fm = 0; fm < 4; ++fm) {
        const size_t rowb = brow + wm * 64 + fm * 16 + fq * 4;
#pragma unroll
        for (int fn = 0; fn < 4; ++fn) {
            const int col = bcol + wn * 64 + fn * 16 + fr;
            if (col < N) {
                const float bv = bias[col];
#pragma unroll
                for (int r = 0; r < 4; ++r) {
                    float v = acc[fm][fn][r] + bv;
                    if (RELU) v = fmaxf(v, 0.f);
                    const size_t idx = (rowb + r) * (size_t)ldc + col;
                    if (OBF16) ((ushort_t*)C)[idx] = f2bf(v);
                    else       ((float*)C)[idx]    = v;
                }
            }
        }
    }
}

// ---------------------------------------------------------------------------
// ONE merged prep kernel: all weight transposes + bias packs.
// ---------------------------------------------------------------------------
__device__ __forceinline__ void dev_transpose(const float* W, ushort_t* Wt,
                                              int K, int N, int Npad, int idx)
{
    if (idx >= Npad * K) return;
    int n = idx / K, k = idx - n * K;
    float v = (n < N) ? W[(size_t)k * N + n] : 0.f;
    Wt[idx] = f2bf(v);
}
__device__ __forceinline__ void dev_transpose_k(const float* W, ushort_t* Wt,
                                                int Ksrc, int N, int ldk,
                                                int kOff, float sign, int idx)
{
    if (idx >= N * Ksrc) return;
    int n = idx / Ksrc, k = idx - n * Ksrc;
    Wt[(size_t)n * ldk + kOff + k] = f2bf(sign * W[(size_t)k * N + n]);
}

__global__ __launch_bounds__(256)
void prep_all(const float* __restrict__ Wt1, const float* __restrict__ Wp1,
              const float* __restrict__ Wp2, const float* __restrict__ Wt2,
              const float* __restrict__ Wp3, const float* __restrict__ Wk,
              const float* __restrict__ Wq,  const float* __restrict__ Wv,
              const float* __restrict__ Wc,  const float* __restrict__ W2,
              const float* __restrict__ bt1, const float* __restrict__ bp1,
              const float* __restrict__ bk,  const float* __restrict__ bq,
              const float* __restrict__ bv,  const float* __restrict__ bt2,
              const float* __restrict__ bp3,
              ushort_t* __restrict__ Bg1, ushort_t* __restrict__ Wp2t,
              ushort_t* __restrict__ Dt,  ushort_t* __restrict__ Wkvq,
              ushort_t* __restrict__ Wct, ushort_t* __restrict__ W2t,
              float* __restrict__ g1bias, float* __restrict__ pbias,
              float* __restrict__ cbias)
{
    const int b = blockIdx.x;
    const int t = threadIdx.x;
    if (b < 1024)        dev_transpose(Wt1, Bg1,             512, 512, 512, (b - 0)    * 256 + t);
    else if (b < 2048)   dev_transpose(Wp1, Bg1 + 512 * 512, 512, 512, 512, (b - 1024) * 256 + t);
    else if (b < 3072)   dev_transpose(Wp2, Wp2t,            512, 512, 512, (b - 2048) * 256 + t);
    else if (b < 3328)   dev_transpose_k(Wt2, Dt, 512, 128, 1024, 0,    1.f, (b - 3072) * 256 + t);
    else if (b < 3584)   dev_transpose_k(Wp3, Dt, 512, 128, 1024, 512, -1.f, (b - 3328) * 256 + t);
    else if (b < 3616)   dev_transpose(Wk, Wkvq + 0 * 256,   256, 32, 32,   (b - 3584) * 256 + t);
    else if (b < 3648)   dev_transpose(Wq, Wkvq + 32 * 256,  256, 32, 32,   (b - 3616) * 256 + t);
    else if (b < 3776)   dev_transpose(Wv, Wkvq + 64 * 256,  256, 128, 128, (b - 3648) * 256 + t);
    else if (b < 3840)   dev_transpose(Wk, Wkvq + 192 * 256, 256, 0, 64,    (b - 3776) * 256 + t); // zero pad
    else if (b < 4224)   dev_transpose(Wc, Wct, 384, 256, 256, (b - 3840) * 256 + t);
    else if (b < 4352)   dev_transpose(W2, W2t, 256, 64, 128,  (b - 4224) * 256 + t);
    else if (b < 4356) { // g1bias = [bt1 | bp1]
        int j = (b - 4352) * 256 + t;
        if (j < 512) g1bias[j] = bt1[j];
        else         g1bias[j] = bp1[j - 512];
    } else if (b == 4356) { // pbias
        float v = 0.f;
        if      (t < 32)  v = bk[t];
        else if (t < 64)  v = bq[t - 32];
        else if (t < 192) v = bv[t - 64];
        pbias[t] = v;
    } else {              // cbias
        if (t < 128) cbias[t] = bt2[t] - bp3[t];
    }
}

__global__ __launch_bounds__(256)
void conv_f32_bf16(const float* __restrict__ src, ushort_t* __restrict__ dst)
{
    size_t q = (size_t)blockIdx.x * 256 + threadIdx.x;
    float4 v = ((const float4*)src)[q];
    ushort_t* d = dst + q * 4;
    d[0] = f2bf(v.x); d[1] = f2bf(v.y); d[2] = f2bf(v.z); d[3] = f2bf(v.w);
}

// ---------------------------------------------------------------------------
// attention: kvq packed [BA][192] bf16; vectorized staging (uint / uint4).
// ---------------------------------------------------------------------------
__global__ __launch_bounds__(256)
void attn_apply(const ushort_t* __restrict__ kvq, const float* __restrict__ Wa,
                const float* __restrict__ ba, const float* __restrict__ iimp,
                ushort_t* __restrict__ applied)
{
    const int b = blockIdx.x, t = threadIdx.x;
    __shared__ float klds[512], qlds[512];
    __shared__ ushort_t vlds[2048];
    __shared__ float part[16][17];
    __shared__ float kp[16];
    __shared__ float attn[16][17];

    {
        const int i = t * 2;
        const int a = i >> 5, c = i & 31;
        const size_t base = ((size_t)b * AA + a) * 192;
        const uint32_t uk = *(const uint32_t*)(kvq + base + c);
        const uint32_t uq = *(const uint32_t*)(kvq + base + 32 + c);
        klds[i]     = bf2f((ushort_t)(uk & 0xffff));
        klds[i + 1] = bf2f((ushort_t)(uk >> 16));
        qlds[i]     = bf2f((ushort_t)(uq & 0xffff));
        qlds[i + 1] = bf2f((ushort_t)(uq >> 16));
    }
    {
        const int j = t >> 4, e = t & 15;
        const uint4 v = *(const uint4*)(kvq + ((size_t)b * AA + j) * 192 + 64 + e * 8);
        *(uint4*)&vlds[j * 128 + e * 8] = v;
    }
    __syncthreads();

    {
        int j = t & 15, seg = t >> 4;
        float s = 0.f;
        for (int c = seg * 32; c < seg * 32 + 32; ++c)
            s += klds[c] * Wa[(32 + c) * 16 + j];
        part[j][seg] = s;
    }
    __syncthreads();
    if (t < 16) {
        float s = 0.f;
#pragma unroll
        for (int seg = 0; seg < 16; ++seg) s += part[t][seg];
        kp[t] = s;
    }
    __syncthreads();

    {
        int i = t >> 4, j = t & 15;
        float s = 0.f;
#pragma unroll
        for (int q = 0; q < 32; ++q) s += qlds[i * 32 + q] * Wa[q * 16 + j];
        attn[i][j] = s + kp[j] + ba[j];
    }
    __syncthreads();
    if (t < 16) {
        float mx = -1e30f;
#pragma unroll
        for (int j = 0; j < 16; ++j) mx = fmaxf(mx, attn[t][j]);
        float e[16], den = 0.f;
#pragma unroll
        for (int j = 0; j < 16; ++j) { e[j] = __expf(attn[t][j] - mx); den += e[j]; }
        float inv = 1.f / den;
#pragma unroll
        for (int j = 0; j < 16; ++j)
            attn[t][j] = e[j] * inv + 0.5f * iimp[b * 16 + j];
    }
    __syncthreads();

    for (int o = t; o < 2048; o += 256) {
        int i = o >> 7, v = o & 127;
        float s = 0.f;
#pragma unroll
        for (int j = 0; j < 16; ++j) s += attn[i][j] * bf2f(vlds[j * 128 + v]);
        applied[((size_t)b * AA + i) * 128 + v] = f2bf(s);
    }
}

// ---------------------------------------------------------------------------
// launch
// ---------------------------------------------------------------------------
extern "C" void kernel_launch(void* const* d_in, const int* in_sizes, int n_in,
                              void* d_out, int out_size, void* d_ws, size_t ws_size,
                              hipStream_t stream)
{
    const float* x      = (const float*)d_in[0];
    const float* hidden = (const float*)d_in[1];
    const float* Wk  = (const float*)d_in[2];
    const float* bk  = (const float*)d_in[3];
    const float* Wv  = (const float*)d_in[4];
    const float* bv  = (const float*)d_in[5];
    const float* Wq  = (const float*)d_in[6];
    const float* bq  = (const float*)d_in[7];
    const float* Wa  = (const float*)d_in[8];
    const float* ba  = (const float*)d_in[9];
    const float* Wt1 = (const float*)d_in[10];
    const float* bt1 = (const float*)d_in[11];
    const float* Wt2 = (const float*)d_in[12];
    const float* bt2 = (const float*)d_in[13];
    const float* Wp1 = (const float*)d_in[14];
    const float* bp1 = (const float*)d_in[15];
    const float* Wp2 = (const float*)d_in[16];
    const float* bp2 = (const float*)d_in[17];
    const float* Wp3 = (const float*)d_in[18];
    const float* bp3 = (const float*)d_in[19];
    const float* Wc  = (const float*)d_in[20];
    const float* bc  = (const float*)d_in[21];
    const float* W2  = (const float*)d_in[22];
    const float* b2  = (const float*)d_in[23];

    float*    out = (float*)d_out;
    ushort_t* ws  = (ushort_t*)d_ws;

    ushort_t* xb  = ws;                        // [BA*512] x bf16
    ushort_t* ht2 = xb + (size_t)BA * 512;     // [BA*1024] [h_t | h_p1]
    ushort_t* hp2 = ht2 + (size_t)BA * 1024;   // [BA*512] h_p2
    ushort_t* WT  = hp2 + (size_t)BA * 512;
    ushort_t* kvq     = xb;
    ushort_t* hiddenb = hp2;
    ushort_t* applied = ht2;

    ushort_t* Bg1  = WT;                    // 1024*512
    ushort_t* Wp2t = Bg1  + 1024 * 512;     // 512*512
    ushort_t* Dt   = Wp2t + 512 * 512;      // 128*1024
    ushort_t* Wkvq = Dt   + 128 * 1024;     // 256*256
    ushort_t* Wct  = Wkvq + 256 * 256;      // 256*384
    ushort_t* W2t  = Wct  + 256 * 384;      // 128*256
    float* g1bias = (float*)(W2t + 128 * 256);
    float* pbias  = g1bias + 1024;
    float* cbias  = pbias + 256;
    float* iimp   = cbias + 128;

    const dim3 blk(256);
    const int BIG = 1 << 30;

    prep_all<<<4358, blk, 0, stream>>>(
        Wt1, Wp1, Wp2, Wt2, Wp3, Wk, Wq, Wv, Wc, W2,
        bt1, bp1, bk, bq, bv, bt2, bp3,
        Bg1, Wp2t, Dt, Wkvq, Wct, W2t, g1bias, pbias, cbias);

    conv_f32_bf16<<<65536, blk, 0, stream>>>(x, xb);
    gemm8p<true, false><<<2048, 512, 0, stream>>>(
        xb, 512, xb, 512, BIG, Bg1, g1bias, ht2, 1024, 512, 2, 64, nullptr, nullptr);
    gemm8p<true, false><<<1024, 512, 0, stream>>>(
        ht2 + 512, 1024, ht2 + 512, 1024, BIG, Wp2t, bp2, hp2, 512, 512, 1, 64, nullptr, nullptr);
    gemm_mfma<true, false, true><<<1024, blk, 0, stream>>>(
        ht2, 1024, hp2, 512, 512, Dt, cbias, nullptr, 128, 128, 1024, 0, iimp);

    conv_f32_bf16<<<32768, blk, 0, stream>>>(hidden, hiddenb);
    gemm_mfma<true, false, false><<<2048, blk, 0, stream>>>(
        hiddenb, 256, hiddenb, 256, BIG, Wkvq, pbias, kvq, 192, 192, 256, 1, nullptr);
    attn_apply<<<BB, blk, 0, stream>>>(kvq, Wa, ba, iimp, applied);

    gemm8p<true, true><<<512, 512, 0, stream>>>(
        applied, 128, hiddenb, 256, 128, Wct, bc, (ushort_t*)out, 64, 384, 0, 64, W2t, b2);
}